// Round 4
// baseline (637.388 us; speedup 1.0000x reference)
//
#include <hip/hip_runtime.h>
#include <hip/hip_bf16.h>
#include <stdint.h>

// ---------------------------------------------------------------------------
// NRI-style MLP encoder. B=32, T=50, N=100, D=4, E=9900, H=256.
// I/O dtype: FLOAT32 (reference is all fp32; R2/R3 NaN was fp32-read-as-bf16).
// Internal: bf16 MFMA with fp32 accumulation; U/C4/biases/Wf kept fp32.
// Fused formulation (per recv-group (b,i), 99 edges, send j = k+(k>=i)):
//   U   = h @ W2a_recv + b2a                      (3200x256, fp32)
//   t2k = relu(U[b,i] + h_j @ W2a_send)
//   S   = (sum_k t2k)/100 ; vin = S@w2b + 0.99 b2b    [sum-before-GEMM]
//   v2  = mlp3(vin)
//   C4  = v2 @ W4a_recv + (b4a + b2b@W4a_e)       (3200x256, fp32)
//   z4k = relu(C4[b,i] + v2_j @ W4a_send + t2k @ (w2b@W4a_e))
//   out = z4 @ (w4b@wo) + (b4b@wo + bo)           (fp32 out)
// e (316800x256) never materialized. Workspace ~11 MB.
// Slot liveness: SL_h=h | SL_U=U | SL_3=t1,vin,v2 | SL_4=hin,Ssc,t3,C4.
// Order: repack->g1(t1)->g2(h)->g3(U)->A(Ssc)->g4(vin)->g5(t3)->g6(v2)
//        ->g7(C4)->B(out); all live ranges disjoint per slot.
// ---------------------------------------------------------------------------

typedef __attribute__((ext_vector_type(8))) short short8;
typedef __attribute__((ext_vector_type(4))) float float4v;

__device__ inline float bf2f(unsigned short u) {
    union { unsigned int i; float f; } v; v.i = ((unsigned int)u) << 16; return v.f;
}
__device__ inline unsigned short f2bf(float f) {
    union { float f; unsigned int i; } v; v.f = f;
    unsigned int i = v.i;
    return (unsigned short)((i + 0x7FFFu + ((i >> 16) & 1u)) >> 16);
}

// ---- pack weight K x 256 fp32 (row-major) -> bf16 Wp[kb][n][kk] ----
__global__ __launch_bounds__(256) void pack_w_kernel(
        const float* __restrict__ W, unsigned short* __restrict__ Wp,
        int Kin, int Kp) {
    int idx = blockIdx.x * 256 + threadIdx.x;
    if (idx >= Kp * 256) return;
    int k = idx >> 8;
    int n = idx & 255;
    unsigned short v = (k < Kin) ? f2bf(W[k * 256 + n]) : (unsigned short)0;
    Wp[((size_t)(k >> 5) * 256 + n) * 32 + (k & 31)] = v;
}

// ---- x (B,T,N,D) fp32 -> hin (B*N, 224) bf16, zero pad cols 200..223 ----
__global__ __launch_bounds__(256) void repack_x_kernel(
        const float* __restrict__ x, unsigned short* __restrict__ hin) {
    int idx = blockIdx.x * 256 + threadIdx.x;
    if (idx >= 3200 * 224) return;
    int row = idx / 224;
    int c = idx - row * 224;
    int b = row / 100, n = row - b * 100;
    unsigned short v = 0;
    if (c < 200) {
        int t = c >> 2, d = c & 3;
        v = f2bf(x[(((size_t)(b * 50 + t)) * 100 + n) * 4 + d]);
    }
    hin[(size_t)row * 224 + c] = v;
}

// ---- Wf = w4b @ wo (256x4 fp32), bfv = b4b @ wo + bo ----
__global__ __launch_bounds__(256) void fuse_wo_kernel(
        const float* __restrict__ w4b, const float* __restrict__ b4b,
        const float* __restrict__ wo, const float* __restrict__ bo,
        float* __restrict__ Wf, float* __restrict__ bfv) {
    int k = threadIdx.x;
    float a[4] = {0.f, 0.f, 0.f, 0.f};
    for (int c = 0; c < 256; ++c) {
        float wv = w4b[k * 256 + c];
        #pragma unroll
        for (int o = 0; o < 4; ++o) a[o] += wv * wo[c * 4 + o];
    }
    #pragma unroll
    for (int o = 0; o < 4; ++o) Wf[k * 4 + o] = a[o];
    if (k < 4) {
        float s = bo[k];
        for (int c = 0; c < 256; ++c) s += b4b[c] * wo[c * 4 + k];
        bfv[k] = s;
    }
}

// ---- W2b4 = w2b @ w4a[512:768] -> bf16 packed into Wp4z kb 8..15 ----
__global__ __launch_bounds__(256) void fuse_w2b4_kernel(
        const float* __restrict__ w2b, const float* __restrict__ w4a,
        unsigned short* __restrict__ Wp4z) {
    int k = blockIdx.x;      // 0..255 (t2 feature)
    int c = threadIdx.x;     // 0..255 (hidden out)
    float s = 0.f;
    for (int t = 0; t < 256; ++t)
        s += w2b[k * 256 + t] * w4a[(size_t)(512 + t) * 256 + c];
    Wp4z[((size_t)(8 + (k >> 5)) * 256 + c) * 32 + (k & 31)] = f2bf(s);
}

// ---- b4a' = b4a + b2b @ w4a[512:768] ; b2bs = 0.99*b2b  (fp32) ----
__global__ __launch_bounds__(256) void prep_bias_kernel(
        const float* __restrict__ b4a, const float* __restrict__ b2b,
        const float* __restrict__ w4a,
        float* __restrict__ b4ap, float* __restrict__ b2bs) {
    int c = threadIdx.x;
    float s = b4a[c];
    for (int k = 0; k < 256; ++k)
        s += b2b[k] * w4a[(size_t)(512 + k) * 256 + c];
    b4ap[c] = s;
    b2bs[c] = 0.99f * b2b[c];
}

// ---------------------------------------------------------------------------
// Node GEMM: C(3200x256) = act(A_bf16(3200xK) @ Wp_bf16 + bias_f32). Grid 50.
// OUTF32: write fp32 (for U/C4); else bf16.
// ---------------------------------------------------------------------------
template <bool RELU, bool OUTF32>
__global__ __launch_bounds__(256, 2) void gemm_kernel(
        const unsigned short* __restrict__ A,
        const unsigned short* __restrict__ Bp,
        const float* __restrict__ bias,
        void* __restrict__ Cv, int K) {
    const int tid  = threadIdx.x;
    const int wave = tid >> 6;
    const int lane = tid & 63;
    const int l15  = lane & 15;
    const int quad = lane >> 4;
    const int m_base = blockIdx.x * 64;
    const int n0   = wave * 64;
    const int koff = quad * 8;

    float4v acc[4][4];
    #pragma unroll
    for (int mi = 0; mi < 4; ++mi)
        #pragma unroll
        for (int ni = 0; ni < 4; ++ni) acc[mi][ni] = (float4v)(0.0f);

    const int KB = K >> 5;
    for (int kb = 0; kb < KB; ++kb) {
        short8 af[4], bf[4];
        #pragma unroll
        for (int mi = 0; mi < 4; ++mi)
            af[mi] = *(const short8*)(A + (size_t)(m_base + mi * 16 + l15) * K + kb * 32 + koff);
        #pragma unroll
        for (int ni = 0; ni < 4; ++ni)
            bf[ni] = *(const short8*)(Bp + ((size_t)kb * 256 + n0 + ni * 16 + l15) * 32 + koff);
        #pragma unroll
        for (int mi = 0; mi < 4; ++mi)
            #pragma unroll
            for (int ni = 0; ni < 4; ++ni)
                acc[mi][ni] = __builtin_amdgcn_mfma_f32_16x16x32_bf16(af[mi], bf[ni], acc[mi][ni], 0, 0, 0);
    }

    #pragma unroll
    for (int ni = 0; ni < 4; ++ni) {
        int col = n0 + ni * 16 + l15;
        float bv = bias[col];
        #pragma unroll
        for (int mi = 0; mi < 4; ++mi) {
            int rowb = m_base + mi * 16 + quad * 4;
            #pragma unroll
            for (int r = 0; r < 4; ++r) {
                float v = acc[mi][ni][r] + bv;
                if (RELU) v = v > 0.f ? v : 0.f;
                if (OUTF32) ((float*)Cv)[(size_t)(rowb + r) * 256 + col] = v;
                else ((unsigned short*)Cv)[(size_t)(rowb + r) * 256 + col] = f2bf(v);
            }
        }
    }
}

// ---------------------------------------------------------------------------
// Phase A: per recv-group, t2 GEMM (99x256 @ 256x256) + relu + column-sum.
// Grid 3200, block 256 (4 waves x 64 cols). M padded 99->112 (7 frags).
// ---------------------------------------------------------------------------
__global__ __launch_bounds__(256, 2) void edge_phaseA_kernel(
        const unsigned short* __restrict__ h, const float* __restrict__ U,
        const unsigned short* __restrict__ Wp2s, unsigned short* __restrict__ Ssc) {
    const int g = blockIdx.x;
    const int b = g / 100, nr = g - b * 100;
    const int tid  = threadIdx.x;
    const int wave = tid >> 6;
    const int lane = tid & 63;
    const int l15  = lane & 15;
    const int quad = lane >> 4;
    const int n0   = wave * 64;
    const int koff = quad * 8;

    int jrow[7];
    #pragma unroll
    for (int mi = 0; mi < 7; ++mi) {
        int k = mi * 16 + l15;
        int j = (k < 99) ? (k + (k >= nr ? 1 : 0)) : 0;
        jrow[mi] = b * 100 + j;
    }

    float4v acc[7][4];
    #pragma unroll
    for (int mi = 0; mi < 7; ++mi)
        #pragma unroll
        for (int ni = 0; ni < 4; ++ni) acc[mi][ni] = (float4v)(0.0f);

    #pragma unroll
    for (int kb = 0; kb < 8; ++kb) {
        short8 af[7], bf[4];
        #pragma unroll
        for (int mi = 0; mi < 7; ++mi)
            af[mi] = *(const short8*)(h + (size_t)jrow[mi] * 256 + kb * 32 + koff);
        #pragma unroll
        for (int ni = 0; ni < 4; ++ni)
            bf[ni] = *(const short8*)(Wp2s + ((size_t)kb * 256 + n0 + ni * 16 + l15) * 32 + koff);
        #pragma unroll
        for (int mi = 0; mi < 7; ++mi)
            #pragma unroll
            for (int ni = 0; ni < 4; ++ni)
                acc[mi][ni] = __builtin_amdgcn_mfma_f32_16x16x32_bf16(af[mi], bf[ni], acc[mi][ni], 0, 0, 0);
    }

    const float* Up = U + (size_t)g * 256;
    #pragma unroll
    for (int ni = 0; ni < 4; ++ni) {
        int col = n0 + ni * 16 + l15;
        float u = Up[col];
        float cs = 0.f;
        #pragma unroll
        for (int mi = 0; mi < 7; ++mi) {
            int rowb = mi * 16 + quad * 4;
            #pragma unroll
            for (int r = 0; r < 4; ++r) {
                if (rowb + r < 99) {
                    float v = u + acc[mi][ni][r];
                    cs += (v > 0.f ? v : 0.f);
                }
            }
        }
        cs += __shfl_xor(cs, 16, 64);
        cs += __shfl_xor(cs, 32, 64);
        if (quad == 0) Ssc[(size_t)g * 256 + col] = f2bf(cs * 0.01f);
    }
}

// ---------------------------------------------------------------------------
// Phase B: per recv-group: t2 GEMM -> LDS; z4 GEMM (K=512: v2 gather | t2 LDS);
// fused out = relu(z4) @ Wf + bfv in epilogue. Grid 3200, block 256.
// LDS t2 stride 264 elem (528 B): 16B-aligned rows, 2-way bank alias (free).
// ---------------------------------------------------------------------------
__global__ __launch_bounds__(256, 2) void edge_phaseB_kernel(
        const unsigned short* __restrict__ h, const unsigned short* __restrict__ v2,
        const float* __restrict__ U, const float* __restrict__ C4,
        const unsigned short* __restrict__ Wp2s, const unsigned short* __restrict__ Wp4z,
        const float* __restrict__ Wf, const float* __restrict__ bfv,
        float* __restrict__ out) {
    __shared__ __align__(16) unsigned short t2s[112 * 264]; // 59136 B
    const int g = blockIdx.x;
    const int b = g / 100, nr = g - b * 100;
    const int tid  = threadIdx.x;
    const int wave = tid >> 6;
    const int lane = tid & 63;
    const int l15  = lane & 15;
    const int quad = lane >> 4;
    const int n0   = wave * 64;
    const int koff = quad * 8;

    int jrow[7];
    #pragma unroll
    for (int mi = 0; mi < 7; ++mi) {
        int k = mi * 16 + l15;
        int j = (k < 99) ? (k + (k >= nr ? 1 : 0)) : 0;
        jrow[mi] = b * 100 + j;
    }

    // ---- stage 1: t2 tile -> LDS ----
    {
        float4v acc[7][4];
        #pragma unroll
        for (int mi = 0; mi < 7; ++mi)
            #pragma unroll
            for (int ni = 0; ni < 4; ++ni) acc[mi][ni] = (float4v)(0.0f);

        #pragma unroll
        for (int kb = 0; kb < 8; ++kb) {
            short8 af[7], bf[4];
            #pragma unroll
            for (int mi = 0; mi < 7; ++mi)
                af[mi] = *(const short8*)(h + (size_t)jrow[mi] * 256 + kb * 32 + koff);
            #pragma unroll
            for (int ni = 0; ni < 4; ++ni)
                bf[ni] = *(const short8*)(Wp2s + ((size_t)kb * 256 + n0 + ni * 16 + l15) * 32 + koff);
            #pragma unroll
            for (int mi = 0; mi < 7; ++mi)
                #pragma unroll
                for (int ni = 0; ni < 4; ++ni)
                    acc[mi][ni] = __builtin_amdgcn_mfma_f32_16x16x32_bf16(af[mi], bf[ni], acc[mi][ni], 0, 0, 0);
        }
        const float* Up = U + (size_t)g * 256;
        #pragma unroll
        for (int ni = 0; ni < 4; ++ni) {
            int col = n0 + ni * 16 + l15;
            float u = Up[col];
            #pragma unroll
            for (int mi = 0; mi < 7; ++mi) {
                int rowb = mi * 16 + quad * 4;
                #pragma unroll
                for (int r = 0; r < 4; ++r) {
                    float v = u + acc[mi][ni][r];
                    v = v > 0.f ? v : 0.f;
                    t2s[(rowb + r) * 264 + col] = f2bf(v);
                }
            }
        }
    }
    __syncthreads();

    // ---- stage 2: z4 GEMM (K=512) ----
    float4v acc2[7][4];
    #pragma unroll
    for (int mi = 0; mi < 7; ++mi)
        #pragma unroll
        for (int ni = 0; ni < 4; ++ni) acc2[mi][ni] = (float4v)(0.0f);

    #pragma unroll
    for (int kb = 0; kb < 16; ++kb) {
        short8 af[7], bf[4];
        #pragma unroll
        for (int mi = 0; mi < 7; ++mi) {
            if (kb < 8)
                af[mi] = *(const short8*)(v2 + (size_t)jrow[mi] * 256 + kb * 32 + koff);
            else
                af[mi] = *(const short8*)(&t2s[(mi * 16 + l15) * 264 + (kb - 8) * 32 + koff]);
        }
        #pragma unroll
        for (int ni = 0; ni < 4; ++ni)
            bf[ni] = *(const short8*)(Wp4z + ((size_t)kb * 256 + n0 + ni * 16 + l15) * 32 + koff);
        #pragma unroll
        for (int mi = 0; mi < 7; ++mi)
            #pragma unroll
            for (int ni = 0; ni < 4; ++ni)
                acc2[mi][ni] = __builtin_amdgcn_mfma_f32_16x16x32_bf16(af[mi], bf[ni], acc2[mi][ni], 0, 0, 0);
    }
    __syncthreads();            // all t2s reads done; safe to alias as partials

    float* part = (float*)t2s;  // [4][112][4] floats = 7168 B
    const float* Cp = C4 + (size_t)g * 256;
    float c4v[4], wfv[4][4];
    #pragma unroll
    for (int ni = 0; ni < 4; ++ni) {
        int col = n0 + ni * 16 + l15;
        c4v[ni] = Cp[col];
        #pragma unroll
        for (int o = 0; o < 4; ++o) wfv[ni][o] = Wf[col * 4 + o];
    }
    #pragma unroll
    for (int mi = 0; mi < 7; ++mi) {
        #pragma unroll
        for (int r = 0; r < 4; ++r) {
            float p0 = 0.f, p1 = 0.f, p2 = 0.f, p3 = 0.f;
            #pragma unroll
            for (int ni = 0; ni < 4; ++ni) {
                float zv = c4v[ni] + acc2[mi][ni][r];
                zv = zv > 0.f ? zv : 0.f;
                p0 += zv * wfv[ni][0];
                p1 += zv * wfv[ni][1];
                p2 += zv * wfv[ni][2];
                p3 += zv * wfv[ni][3];
            }
            #pragma unroll
            for (int m = 1; m <= 8; m <<= 1) {
                p0 += __shfl_xor(p0, m, 64);
                p1 += __shfl_xor(p1, m, 64);
                p2 += __shfl_xor(p2, m, 64);
                p3 += __shfl_xor(p3, m, 64);
            }
            if (l15 == 0) {
                int row = mi * 16 + quad * 4 + r;
                float* pp = part + ((size_t)(wave * 112 + row)) * 4;
                pp[0] = p0; pp[1] = p1; pp[2] = p2; pp[3] = p3;
            }
        }
    }
    __syncthreads();

    for (int idx = tid; idx < 448; idx += 256) {
        int row = idx >> 2, o = idx & 3;
        if (row < 99) {
            float s = part[(size_t)(0 * 112 + row) * 4 + o] + part[(size_t)(1 * 112 + row) * 4 + o]
                    + part[(size_t)(2 * 112 + row) * 4 + o] + part[(size_t)(3 * 112 + row) * 4 + o]
                    + bfv[o];
            out[((size_t)b * 9900 + nr * 99 + row) * 4 + o] = s;
        }
    }
}

extern "C" void kernel_launch(void* const* d_in, const int* in_sizes, int n_in,
                              void* d_out, int out_size, void* d_ws, size_t ws_size,
                              hipStream_t stream) {
    const float* x   = (const float*)d_in[0];
    const float* w1a = (const float*)d_in[3];
    const float* b1a = (const float*)d_in[4];
    const float* w1b = (const float*)d_in[5];
    const float* b1b = (const float*)d_in[6];
    const float* w2a = (const float*)d_in[7];
    const float* b2a = (const float*)d_in[8];
    const float* w2b = (const float*)d_in[9];
    const float* b2b = (const float*)d_in[10];
    const float* w3a = (const float*)d_in[11];
    const float* b3a = (const float*)d_in[12];
    const float* w3b = (const float*)d_in[13];
    const float* b3b = (const float*)d_in[14];
    const float* w4a = (const float*)d_in[15];
    const float* b4a = (const float*)d_in[16];
    const float* w4b = (const float*)d_in[17];
    const float* b4b = (const float*)d_in[18];
    const float* wo  = (const float*)d_in[19];
    const float* bo  = (const float*)d_in[20];
    float* out = (float*)d_out;
    (void)in_sizes; (void)n_in; (void)out_size; (void)ws_size;

    char* ws = (char*)d_ws;
    size_t off = 0;
    auto alloc = [&](size_t bytes) {
        size_t o = off;
        off = (off + bytes + 255) & ~(size_t)255;
        return o;
    };
    const size_t SLOT_BF = (size_t)3200 * 256 * 2;   // 1.64 MB
    const size_t SLOT_F  = (size_t)3200 * 256 * 4;   // 3.28 MB
    unsigned short* S_h  = (unsigned short*)(ws + alloc(SLOT_BF)); // h persistent
    float*          S_U  = (float*)(ws + alloc(SLOT_F));           // U persistent
    unsigned short* S_3  = (unsigned short*)(ws + alloc(SLOT_BF)); // t1 -> vin -> v2
    char*           S_4  = (char*)(ws + alloc(SLOT_F));            // hin -> Ssc -> t3 -> C4
    unsigned short* Wp1a = (unsigned short*)(ws + alloc(224 * 256 * 2));
    unsigned short* Wp1b = (unsigned short*)(ws + alloc(256 * 256 * 2));
    unsigned short* Wp2r = (unsigned short*)(ws + alloc(256 * 256 * 2));
    unsigned short* Wp2s = (unsigned short*)(ws + alloc(256 * 256 * 2));
    unsigned short* Wp2b = (unsigned short*)(ws + alloc(256 * 256 * 2));
    unsigned short* Wp3a = (unsigned short*)(ws + alloc(256 * 256 * 2));
    unsigned short* Wp3b = (unsigned short*)(ws + alloc(256 * 256 * 2));
    unsigned short* Wp4r = (unsigned short*)(ws + alloc(256 * 256 * 2));
    unsigned short* Wp4z = (unsigned short*)(ws + alloc(512 * 256 * 2));
    float*          Wf   = (float*)(ws + alloc(256 * 4 * 4));
    float*          bfv  = (float*)(ws + alloc(4 * 4));
    float*          b4ap = (float*)(ws + alloc(256 * 4));
    float*          b2bs = (float*)(ws + alloc(256 * 4));
    // total ~11.2 MB

    unsigned short* hin = (unsigned short*)S_4; // [repack, g1]
    unsigned short* Ssc = (unsigned short*)S_4; // [A, g4]
    unsigned short* t3  = (unsigned short*)S_4; // [g5, g6]
    float*          C4  = (float*)S_4;          // [g7, B]
    unsigned short* t1  = S_3;                  // [g1, g2]
    unsigned short* vin = S_3;                  // [g4, g5]
    unsigned short* v2  = S_3;                  // [g6, B]

    // ---- prep: packing + fusions ----
    hipLaunchKernelGGL(pack_w_kernel, dim3(224), dim3(256), 0, stream, w1a, Wp1a, 200, 224);
    hipLaunchKernelGGL(pack_w_kernel, dim3(256), dim3(256), 0, stream, w1b, Wp1b, 256, 256);
    hipLaunchKernelGGL(pack_w_kernel, dim3(256), dim3(256), 0, stream, w2a, Wp2r, 256, 256);
    hipLaunchKernelGGL(pack_w_kernel, dim3(256), dim3(256), 0, stream, w2a + 256 * 256, Wp2s, 256, 256);
    hipLaunchKernelGGL(pack_w_kernel, dim3(256), dim3(256), 0, stream, w2b, Wp2b, 256, 256);
    hipLaunchKernelGGL(pack_w_kernel, dim3(256), dim3(256), 0, stream, w3a, Wp3a, 256, 256);
    hipLaunchKernelGGL(pack_w_kernel, dim3(256), dim3(256), 0, stream, w3b, Wp3b, 256, 256);
    hipLaunchKernelGGL(pack_w_kernel, dim3(256), dim3(256), 0, stream, w4a, Wp4r, 256, 256);
    hipLaunchKernelGGL(pack_w_kernel, dim3(256), dim3(256), 0, stream, w4a + 256 * 256, Wp4z, 256, 256);
    hipLaunchKernelGGL(fuse_w2b4_kernel, dim3(256), dim3(256), 0, stream, w2b, w4a, Wp4z);
    hipLaunchKernelGGL(fuse_wo_kernel, dim3(1), dim3(256), 0, stream, w4b, b4b, wo, bo, Wf, bfv);
    hipLaunchKernelGGL(prep_bias_kernel, dim3(1), dim3(256), 0, stream, b4a, b2b, w4a, b4ap, b2bs);
    hipLaunchKernelGGL(repack_x_kernel, dim3((3200 * 224 + 255) / 256), dim3(256), 0, stream, x, hin);

    // ---- node MLP1 + U ----
    hipLaunchKernelGGL((gemm_kernel<true,  false>), dim3(50), dim3(256), 0, stream, hin, Wp1a, b1a, (void*)t1,  224); // g1
    hipLaunchKernelGGL((gemm_kernel<false, false>), dim3(50), dim3(256), 0, stream, t1,  Wp1b, b1b, (void*)S_h, 256); // g2
    hipLaunchKernelGGL((gemm_kernel<false, true >), dim3(50), dim3(256), 0, stream, S_h, Wp2r, b2a, (void*)S_U, 256); // g3
    // ---- phase A: t2 + column-sum -> S ----
    hipLaunchKernelGGL(edge_phaseA_kernel, dim3(3200), dim3(256), 0, stream, S_h, S_U, Wp2s, Ssc);
    // ---- vin + node MLP3 + C4 ----
    hipLaunchKernelGGL((gemm_kernel<false, false>), dim3(50), dim3(256), 0, stream, Ssc, Wp2b, b2bs, (void*)vin, 256); // g4
    hipLaunchKernelGGL((gemm_kernel<true,  false>), dim3(50), dim3(256), 0, stream, vin, Wp3a, b3a,  (void*)t3,  256); // g5
    hipLaunchKernelGGL((gemm_kernel<false, false>), dim3(50), dim3(256), 0, stream, t3,  Wp3b, b3b,  (void*)v2,  256); // g6
    hipLaunchKernelGGL((gemm_kernel<false, true >), dim3(50), dim3(256), 0, stream, v2,  Wp4r, b4ap, (void*)C4,  256); // g7
    // ---- phase B: fused t2 -> z4 -> out ----
    hipLaunchKernelGGL(edge_phaseB_kernel, dim3(3200), dim3(256), 0, stream,
                       S_h, v2, S_U, C4, Wp2s, Wp4z, Wf, bfv, out);
}

// Round 6
// 617.075 us; speedup vs baseline: 1.0329x; 1.0329x over previous
//
#include <hip/hip_runtime.h>
#include <hip/hip_bf16.h>
#include <stdint.h>

// ---------------------------------------------------------------------------
// NRI-style MLP encoder. B=32, T=50, N=100, D=4, E=9900, H=256. fp32 I/O.
// Internal: bf16 MFMA, fp32 accum. Fused formulation (R4, verified):
//   U = h@W2a_recv + b2a ; t2k = relu(U_i + h_j@W2a_send)
//   S = (sum_k t2k)/100 ; vin = S@w2b + 0.99 b2b ; v2 = mlp3(vin)
//   C4 = v2@W4a_recv + (b4a + b2b@W4a_e)
//   z4k = relu(C4_i + v2_j@W4a_send + t2k@(w2b@W4a_e))
//   out = z4@(w4b@wo) + (b4b@wo + bo)
// R6 = R5 + one-line fix: Wp4z kb0..7 must pack w4a rows 256..511 (SEND
// block, multiplies v2_j) — R5 wrongly packed rows 512..767. R5's excess
// error (+1.2e-3) matched sqrt(2)*std(z4 contribution) for a wrong-weight
// term; bf16 U/C4/Sp storage contributes only ~1e-5 (kept).
// ---------------------------------------------------------------------------

typedef __attribute__((ext_vector_type(8))) short short8;
typedef __attribute__((ext_vector_type(4))) float float4v;

__device__ inline float bf2f(unsigned short u) {
    union { unsigned int i; float f; } v; v.i = ((unsigned int)u) << 16; return v.f;
}
__device__ inline unsigned short f2bf(float f) {
    union { float f; unsigned int i; } v; v.f = f;
    unsigned int i = v.i;
    return (unsigned short)((i + 0x7FFFu + ((i >> 16) & 1u)) >> 16);
}

// ---- all 9 weight packs in ONE launch. fp32 KxN -> bf16 Wp[kb][n][kk] ----
__global__ __launch_bounds__(256) void pack_all_kernel(
        const float* __restrict__ w1a, const float* __restrict__ w1b,
        const float* __restrict__ w2a, const float* __restrict__ w2b,
        const float* __restrict__ w3a, const float* __restrict__ w3b,
        const float* __restrict__ w4a,
        unsigned short* __restrict__ Wp1a, unsigned short* __restrict__ Wp1b,
        unsigned short* __restrict__ Wp2r, unsigned short* __restrict__ Wp2s,
        unsigned short* __restrict__ Wp2b, unsigned short* __restrict__ Wp3a,
        unsigned short* __restrict__ Wp3b, unsigned short* __restrict__ Wp4r,
        unsigned short* __restrict__ Wp4z) {
    int bx = blockIdx.x;
    const float* W; unsigned short* Wp; int Kin; int b0;
    if      (bx <  224) { W = w1a;             Wp = Wp1a; Kin = 200; b0 = 0;    }
    else if (bx <  480) { W = w1b;             Wp = Wp1b; Kin = 256; b0 = 224;  }
    else if (bx <  736) { W = w2a;             Wp = Wp2r; Kin = 256; b0 = 480;  }
    else if (bx <  992) { W = w2a + 256 * 256; Wp = Wp2s; Kin = 256; b0 = 736;  }
    else if (bx < 1248) { W = w2b;             Wp = Wp2b; Kin = 256; b0 = 992;  }
    else if (bx < 1504) { W = w3a;             Wp = Wp3a; Kin = 256; b0 = 1248; }
    else if (bx < 1760) { W = w3b;             Wp = Wp3b; Kin = 256; b0 = 1504; }
    else if (bx < 2016) { W = w4a;             Wp = Wp4r; Kin = 256; b0 = 1760; }
    else                { W = w4a + 256 * 256; Wp = Wp4z; Kin = 256; b0 = 2016; } // SEND block (R5 bug: was 512*256)
    int idx = (bx - b0) * 256 + threadIdx.x;
    int k = idx >> 8, n = idx & 255;
    unsigned short v = (k < Kin) ? f2bf(W[k * 256 + n]) : (unsigned short)0;
    Wp[((size_t)(k >> 5) * 256 + n) * 32 + (k & 31)] = v;
}

// ---- x (B,T,N,D) fp32 -> hin (B*N, 224) bf16, zero pad cols 200..223 ----
__global__ __launch_bounds__(256) void repack_x_kernel(
        const float* __restrict__ x, unsigned short* __restrict__ hin) {
    int idx = blockIdx.x * 256 + threadIdx.x;
    if (idx >= 3200 * 224) return;
    int row = idx / 224;
    int c = idx - row * 224;
    int b = row / 100, n = row - b * 100;
    unsigned short v = 0;
    if (c < 200) {
        int t = c >> 2, d = c & 3;
        v = f2bf(x[(((size_t)(b * 50 + t)) * 100 + n) * 4 + d]);
    }
    hin[(size_t)row * 224 + c] = v;
}

// ---- W2b4 = w2b @ w4a[512:768] -> bf16 into Wp4z kb 8..15 ----
__global__ __launch_bounds__(256) void fuse_w2b4_kernel(
        const float* __restrict__ w2b, const float* __restrict__ w4a,
        unsigned short* __restrict__ Wp4z) {
    int k = blockIdx.x, c = threadIdx.x;
    float s = 0.f;
    for (int t = 0; t < 256; ++t)
        s += w2b[k * 256 + t] * w4a[(size_t)(512 + t) * 256 + c];
    Wp4z[((size_t)(8 + (k >> 5)) * 256 + c) * 32 + (k & 31)] = f2bf(s);
}

// ---- block 0: Wf=w4b@wo, bfv=b4b@wo+bo ; block 1: b4a'=b4a+b2b@w4a_e, b2bs ----
__global__ __launch_bounds__(256) void fuse_misc_kernel(
        const float* __restrict__ w4b, const float* __restrict__ b4b,
        const float* __restrict__ wo, const float* __restrict__ bo,
        const float* __restrict__ b4a, const float* __restrict__ b2b,
        const float* __restrict__ w4a,
        float* __restrict__ Wf, float* __restrict__ bfv,
        float* __restrict__ b4ap, float* __restrict__ b2bs) {
    int k = threadIdx.x;
    if (blockIdx.x == 0) {
        float a[4] = {0.f, 0.f, 0.f, 0.f};
        for (int c = 0; c < 256; ++c) {
            float wv = w4b[k * 256 + c];
            #pragma unroll
            for (int o = 0; o < 4; ++o) a[o] += wv * wo[c * 4 + o];
        }
        #pragma unroll
        for (int o = 0; o < 4; ++o) Wf[k * 4 + o] = a[o];
        if (k < 4) {
            float s = bo[k];
            for (int c = 0; c < 256; ++c) s += b4b[c] * wo[c * 4 + k];
            bfv[k] = s;
        }
    } else {
        float s = b4a[k];
        for (int t = 0; t < 256; ++t)
            s += b2b[t] * w4a[(size_t)(512 + t) * 256 + k];
        b4ap[k] = s;
        b2bs[k] = 0.99f * b2b[k];
    }
}

// ---------------------------------------------------------------------------
// Node GEMM: C(3200x256) = act(A@Wp + bias). Grid (100,4), block 128 (2 waves).
// ---------------------------------------------------------------------------
template <bool RELU>
__global__ __launch_bounds__(128) void node_gemm_kernel(
        const unsigned short* __restrict__ A,
        const unsigned short* __restrict__ Bp,
        const float* __restrict__ bias,
        unsigned short* __restrict__ C, int K) {
    const int tid  = threadIdx.x;
    const int wave = tid >> 6;
    const int lane = tid & 63;
    const int l15  = lane & 15;
    const int quad = lane >> 4;
    const int m0   = blockIdx.x * 32 + wave * 16;
    const int n0   = blockIdx.y * 64;
    const int koff = quad * 8;

    float4v acc[4];
    #pragma unroll
    for (int ni = 0; ni < 4; ++ni) acc[ni] = (float4v)(0.0f);

    const int KB = K >> 5;
    for (int kb = 0; kb < KB; ++kb) {
        short8 af = *(const short8*)(A + (size_t)(m0 + l15) * K + kb * 32 + koff);
        short8 bf[4];
        #pragma unroll
        for (int ni = 0; ni < 4; ++ni)
            bf[ni] = *(const short8*)(Bp + ((size_t)kb * 256 + n0 + ni * 16 + l15) * 32 + koff);
        #pragma unroll
        for (int ni = 0; ni < 4; ++ni)
            acc[ni] = __builtin_amdgcn_mfma_f32_16x16x32_bf16(af, bf[ni], acc[ni], 0, 0, 0);
    }

    #pragma unroll
    for (int ni = 0; ni < 4; ++ni) {
        int col = n0 + ni * 16 + l15;
        float bv = bias[col];
        #pragma unroll
        for (int r = 0; r < 4; ++r) {
            float v = acc[ni][r] + bv;
            if (RELU) v = v > 0.f ? v : 0.f;
            C[(size_t)(m0 + quad * 4 + r) * 256 + col] = f2bf(v);
        }
    }
}

// ---------------------------------------------------------------------------
// Phase A (M-split): grid (3200,2). hb=0 -> edges 0..49, hb=1 -> 50..98.
// Partial colsums -> Sp[hb] bf16.
// ---------------------------------------------------------------------------
__global__ __launch_bounds__(256, 4) void edge_phaseA_kernel(
        const unsigned short* __restrict__ h, const unsigned short* __restrict__ U,
        const unsigned short* __restrict__ Wp2s, unsigned short* __restrict__ Sp) {
    const int g = blockIdx.x, hb = blockIdx.y;
    const int b = g / 100, nr = g - b * 100;
    const int nrows = hb ? 49 : 50;
    const int k0 = hb * 50;
    const int tid  = threadIdx.x;
    const int wave = tid >> 6;
    const int lane = tid & 63;
    const int l15  = lane & 15;
    const int quad = lane >> 4;
    const int n0   = wave * 64;
    const int koff = quad * 8;

    int jrow[4];
    #pragma unroll
    for (int mi = 0; mi < 4; ++mi) {
        int local = mi * 16 + l15;
        int k = k0 + local;
        int j = (local < nrows) ? (k + (k >= nr ? 1 : 0)) : 0;
        jrow[mi] = b * 100 + j;
    }

    float4v acc[4][4];
    #pragma unroll
    for (int mi = 0; mi < 4; ++mi)
        #pragma unroll
        for (int ni = 0; ni < 4; ++ni) acc[mi][ni] = (float4v)(0.0f);

    #pragma unroll
    for (int kb = 0; kb < 8; ++kb) {
        short8 af[4], bf[4];
        #pragma unroll
        for (int mi = 0; mi < 4; ++mi)
            af[mi] = *(const short8*)(h + (size_t)jrow[mi] * 256 + kb * 32 + koff);
        #pragma unroll
        for (int ni = 0; ni < 4; ++ni)
            bf[ni] = *(const short8*)(Wp2s + ((size_t)kb * 256 + n0 + ni * 16 + l15) * 32 + koff);
        #pragma unroll
        for (int mi = 0; mi < 4; ++mi)
            #pragma unroll
            for (int ni = 0; ni < 4; ++ni)
                acc[mi][ni] = __builtin_amdgcn_mfma_f32_16x16x32_bf16(af[mi], bf[ni], acc[mi][ni], 0, 0, 0);
    }

    const unsigned short* Up = U + (size_t)g * 256;
    #pragma unroll
    for (int ni = 0; ni < 4; ++ni) {
        int col = n0 + ni * 16 + l15;
        float u = bf2f(Up[col]);
        float cs = 0.f;
        #pragma unroll
        for (int mi = 0; mi < 4; ++mi) {
            int rowb = mi * 16 + quad * 4;
            #pragma unroll
            for (int r = 0; r < 4; ++r) {
                if (rowb + r < nrows) {
                    float v = u + acc[mi][ni][r];
                    cs += (v > 0.f ? v : 0.f);
                }
            }
        }
        cs += __shfl_xor(cs, 16, 64);
        cs += __shfl_xor(cs, 32, 64);
        if (quad == 0) Sp[((size_t)hb * 3200 + g) * 256 + col] = f2bf(cs);
    }
}

// ---- Ssc = (Sp0 + Sp1) * 0.01, in-place into Sp0 ----
__global__ __launch_bounds__(256) void combine_kernel(unsigned short* __restrict__ Sp) {
    size_t i = (size_t)blockIdx.x * 256 + threadIdx.x;
    float s = bf2f(Sp[i]) + bf2f(Sp[(size_t)3200 * 256 + i]);
    Sp[i] = f2bf(s * 0.01f);
}

// ---------------------------------------------------------------------------
// Phase B (M-split): grid (3200,2). Stage1 t2(<=50 rows)->LDS; stage2 z4 GEMM
// K=512 (v2 gather | t2 LDS); epilogue fused @Wf projection -> out fp32.
// LDS 64x264x2 = 33792 B -> 4 blocks/CU.
// ---------------------------------------------------------------------------
__global__ __launch_bounds__(256, 4) void edge_phaseB_kernel(
        const unsigned short* __restrict__ h, const unsigned short* __restrict__ v2,
        const unsigned short* __restrict__ U, const unsigned short* __restrict__ C4,
        const unsigned short* __restrict__ Wp2s, const unsigned short* __restrict__ Wp4z,
        const float* __restrict__ Wf, const float* __restrict__ bfv,
        float* __restrict__ out) {
    __shared__ __align__(16) unsigned short t2s[64 * 264]; // 33792 B
    const int g = blockIdx.x, hb = blockIdx.y;
    const int b = g / 100, nr = g - b * 100;
    const int nrows = hb ? 49 : 50;
    const int k0 = hb * 50;
    const int tid  = threadIdx.x;
    const int wave = tid >> 6;
    const int lane = tid & 63;
    const int l15  = lane & 15;
    const int quad = lane >> 4;
    const int n0   = wave * 64;
    const int koff = quad * 8;

    int jrow[4];
    #pragma unroll
    for (int mi = 0; mi < 4; ++mi) {
        int local = mi * 16 + l15;
        int k = k0 + local;
        int j = (local < nrows) ? (k + (k >= nr ? 1 : 0)) : 0;
        jrow[mi] = b * 100 + j;
    }

    // ---- stage 1: t2 half-tile -> LDS ----
    {
        float4v acc[4][4];
        #pragma unroll
        for (int mi = 0; mi < 4; ++mi)
            #pragma unroll
            for (int ni = 0; ni < 4; ++ni) acc[mi][ni] = (float4v)(0.0f);

        #pragma unroll
        for (int kb = 0; kb < 8; ++kb) {
            short8 af[4], bf[4];
            #pragma unroll
            for (int mi = 0; mi < 4; ++mi)
                af[mi] = *(const short8*)(h + (size_t)jrow[mi] * 256 + kb * 32 + koff);
            #pragma unroll
            for (int ni = 0; ni < 4; ++ni)
                bf[ni] = *(const short8*)(Wp2s + ((size_t)kb * 256 + n0 + ni * 16 + l15) * 32 + koff);
            #pragma unroll
            for (int mi = 0; mi < 4; ++mi)
                #pragma unroll
                for (int ni = 0; ni < 4; ++ni)
                    acc[mi][ni] = __builtin_amdgcn_mfma_f32_16x16x32_bf16(af[mi], bf[ni], acc[mi][ni], 0, 0, 0);
        }
        const unsigned short* Up = U + (size_t)g * 256;
        #pragma unroll
        for (int ni = 0; ni < 4; ++ni) {
            int col = n0 + ni * 16 + l15;
            float u = bf2f(Up[col]);
            #pragma unroll
            for (int mi = 0; mi < 4; ++mi) {
                int rowb = mi * 16 + quad * 4;
                #pragma unroll
                for (int r = 0; r < 4; ++r) {
                    float v = u + acc[mi][ni][r];
                    v = v > 0.f ? v : 0.f;
                    t2s[(rowb + r) * 264 + col] = f2bf(v);
                }
            }
        }
    }
    __syncthreads();

    // ---- stage 2: z4 GEMM (K=512) ----
    float4v acc2[4][4];
    #pragma unroll
    for (int mi = 0; mi < 4; ++mi)
        #pragma unroll
        for (int ni = 0; ni < 4; ++ni) acc2[mi][ni] = (float4v)(0.0f);

    #pragma unroll
    for (int kb = 0; kb < 16; ++kb) {
        short8 af[4], bf[4];
        #pragma unroll
        for (int mi = 0; mi < 4; ++mi) {
            if (kb < 8)
                af[mi] = *(const short8*)(v2 + (size_t)jrow[mi] * 256 + kb * 32 + koff);
            else
                af[mi] = *(const short8*)(&t2s[(mi * 16 + l15) * 264 + (kb - 8) * 32 + koff]);
        }
        #pragma unroll
        for (int ni = 0; ni < 4; ++ni)
            bf[ni] = *(const short8*)(Wp4z + ((size_t)kb * 256 + n0 + ni * 16 + l15) * 32 + koff);
        #pragma unroll
        for (int mi = 0; mi < 4; ++mi)
            #pragma unroll
            for (int ni = 0; ni < 4; ++ni)
                acc2[mi][ni] = __builtin_amdgcn_mfma_f32_16x16x32_bf16(af[mi], bf[ni], acc2[mi][ni], 0, 0, 0);
    }
    __syncthreads();            // t2s reads done; alias as fp32 partials

    float* part = (float*)t2s;  // [4 waves][64 rows][4] = 4096 B
    const unsigned short* Cp = C4 + (size_t)g * 256;
    float c4v[4], wfv[4][4];
    #pragma unroll
    for (int ni = 0; ni < 4; ++ni) {
        int col = n0 + ni * 16 + l15;
        c4v[ni] = bf2f(Cp[col]);
        #pragma unroll
        for (int o = 0; o < 4; ++o) wfv[ni][o] = Wf[col * 4 + o];
    }
    #pragma unroll
    for (int mi = 0; mi < 4; ++mi) {
        #pragma unroll
        for (int r = 0; r < 4; ++r) {
            float p0 = 0.f, p1 = 0.f, p2 = 0.f, p3 = 0.f;
            #pragma unroll
            for (int ni = 0; ni < 4; ++ni) {
                float zv = c4v[ni] + acc2[mi][ni][r];
                zv = zv > 0.f ? zv : 0.f;
                p0 += zv * wfv[ni][0];
                p1 += zv * wfv[ni][1];
                p2 += zv * wfv[ni][2];
                p3 += zv * wfv[ni][3];
            }
            #pragma unroll
            for (int m = 1; m <= 8; m <<= 1) {
                p0 += __shfl_xor(p0, m, 64);
                p1 += __shfl_xor(p1, m, 64);
                p2 += __shfl_xor(p2, m, 64);
                p3 += __shfl_xor(p3, m, 64);
            }
            if (l15 == 0) {
                int row = mi * 16 + quad * 4 + r;
                float* pp = part + ((size_t)(wave * 64 + row)) * 4;
                pp[0] = p0; pp[1] = p1; pp[2] = p2; pp[3] = p3;
            }
        }
    }
    __syncthreads();

    {
        int row = tid >> 2, o = tid & 3;
        if (row < nrows) {
            float s = part[(size_t)(0 * 64 + row) * 4 + o] + part[(size_t)(1 * 64 + row) * 4 + o]
                    + part[(size_t)(2 * 64 + row) * 4 + o] + part[(size_t)(3 * 64 + row) * 4 + o]
                    + bfv[o];
            out[((size_t)b * 9900 + nr * 99 + k0 + row) * 4 + o] = s;
        }
    }
}

extern "C" void kernel_launch(void* const* d_in, const int* in_sizes, int n_in,
                              void* d_out, int out_size, void* d_ws, size_t ws_size,
                              hipStream_t stream) {
    const float* x   = (const float*)d_in[0];
    const float* w1a = (const float*)d_in[3];
    const float* b1a = (const float*)d_in[4];
    const float* w1b = (const float*)d_in[5];
    const float* b1b = (const float*)d_in[6];
    const float* w2a = (const float*)d_in[7];
    const float* b2a = (const float*)d_in[8];
    const float* w2b = (const float*)d_in[9];
    const float* b2b = (const float*)d_in[10];
    const float* w3a = (const float*)d_in[11];
    const float* b3a = (const float*)d_in[12];
    const float* w3b = (const float*)d_in[13];
    const float* b3b = (const float*)d_in[14];
    const float* w4a = (const float*)d_in[15];
    const float* b4a = (const float*)d_in[16];
    const float* w4b = (const float*)d_in[17];
    const float* b4b = (const float*)d_in[18];
    const float* wo  = (const float*)d_in[19];
    const float* bo  = (const float*)d_in[20];
    float* out = (float*)d_out;
    (void)in_sizes; (void)n_in; (void)out_size; (void)ws_size;

    char* ws = (char*)d_ws;
    size_t off = 0;
    auto alloc = [&](size_t bytes) {
        size_t o = off;
        off = (off + bytes + 255) & ~(size_t)255;
        return o;
    };
    const size_t SLOT_BF = (size_t)3200 * 256 * 2;   // 1.64 MB
    unsigned short* S_h  = (unsigned short*)(ws + alloc(SLOT_BF));     // h
    unsigned short* S_U  = (unsigned short*)(ws + alloc(SLOT_BF));     // U (bf16)
    unsigned short* S_3  = (unsigned short*)(ws + alloc(SLOT_BF));     // t1 -> vin -> v2
    unsigned short* S_4  = (unsigned short*)(ws + alloc(2 * SLOT_BF)); // hin -> Sp[2] -> Ssc -> t3 -> C4
    unsigned short* Wp1a = (unsigned short*)(ws + alloc(224 * 256 * 2));
    unsigned short* Wp1b = (unsigned short*)(ws + alloc(256 * 256 * 2));
    unsigned short* Wp2r = (unsigned short*)(ws + alloc(256 * 256 * 2));
    unsigned short* Wp2s = (unsigned short*)(ws + alloc(256 * 256 * 2));
    unsigned short* Wp2b = (unsigned short*)(ws + alloc(256 * 256 * 2));
    unsigned short* Wp3a = (unsigned short*)(ws + alloc(256 * 256 * 2));
    unsigned short* Wp3b = (unsigned short*)(ws + alloc(256 * 256 * 2));
    unsigned short* Wp4r = (unsigned short*)(ws + alloc(256 * 256 * 2));
    unsigned short* Wp4z = (unsigned short*)(ws + alloc(512 * 256 * 2));
    float*          Wf   = (float*)(ws + alloc(256 * 4 * 4));
    float*          bfv  = (float*)(ws + alloc(4 * 4));
    float*          b4ap = (float*)(ws + alloc(256 * 4));
    float*          b2bs = (float*)(ws + alloc(256 * 4));
    // total ~9.6 MB

    unsigned short* hin = S_4;                                  // [repack, g1]
    unsigned short* Sp  = S_4;                                  // [A, combine]
    unsigned short* Ssc = S_4;                                  // [combine, g4]
    unsigned short* t3  = (unsigned short*)((char*)S_4 + SLOT_BF); // [g5, g6]
    unsigned short* C4  = S_4;                                  // [g7, B]
    unsigned short* t1  = S_3;                                  // [g1, g2]
    unsigned short* vin = S_3;                                  // [g4, g5]
    unsigned short* v2  = S_3;                                  // [g6, B]

    // ---- prep (4 launches) ----
    hipLaunchKernelGGL(pack_all_kernel, dim3(2272), dim3(256), 0, stream,
                       w1a, w1b, w2a, w2b, w3a, w3b, w4a,
                       Wp1a, Wp1b, Wp2r, Wp2s, Wp2b, Wp3a, Wp3b, Wp4r, Wp4z);
    hipLaunchKernelGGL(fuse_w2b4_kernel, dim3(256), dim3(256), 0, stream, w2b, w4a, Wp4z);
    hipLaunchKernelGGL(fuse_misc_kernel, dim3(2), dim3(256), 0, stream,
                       w4b, b4b, wo, bo, b4a, b2b, w4a, Wf, bfv, b4ap, b2bs);
    hipLaunchKernelGGL(repack_x_kernel, dim3(2800), dim3(256), 0, stream, x, hin);

    // ---- node MLP1 + U ----
    hipLaunchKernelGGL((node_gemm_kernel<true >), dim3(100, 4), dim3(128), 0, stream, hin, Wp1a, b1a, t1,  224); // g1
    hipLaunchKernelGGL((node_gemm_kernel<false>), dim3(100, 4), dim3(128), 0, stream, t1,  Wp1b, b1b, S_h, 256); // g2
    hipLaunchKernelGGL((node_gemm_kernel<false>), dim3(100, 4), dim3(128), 0, stream, S_h, Wp2r, b2a, S_U, 256); // g3
    // ---- phase A (split) + combine ----
    hipLaunchKernelGGL(edge_phaseA_kernel, dim3(3200, 2), dim3(256), 0, stream, S_h, S_U, Wp2s, Sp);
    hipLaunchKernelGGL(combine_kernel, dim3(3200), dim3(256), 0, stream, Sp);
    // ---- vin + node MLP3 + C4 ----
    hipLaunchKernelGGL((node_gemm_kernel<false>), dim3(100, 4), dim3(128), 0, stream, Ssc, Wp2b, b2bs, vin, 256); // g4
    hipLaunchKernelGGL((node_gemm_kernel<true >), dim3(100, 4), dim3(128), 0, stream, vin, Wp3a, b3a,  t3,  256); // g5
    hipLaunchKernelGGL((node_gemm_kernel<false>), dim3(100, 4), dim3(128), 0, stream, t3,  Wp3b, b3b,  v2,  256); // g6
    hipLaunchKernelGGL((node_gemm_kernel<false>), dim3(100, 4), dim3(128), 0, stream, v2,  Wp4r, b4ap, C4,  256); // g7
    // ---- phase B (split, fused projection) ----
    hipLaunchKernelGGL(edge_phaseB_kernel, dim3(3200, 2), dim3(256), 0, stream,
                       S_h, v2, S_U, C4, Wp2s, Wp4z, Wf, bfv, out);
}

// Round 7
// 360.542 us; speedup vs baseline: 1.7679x; 1.7115x over previous
//
#include <hip/hip_runtime.h>
#include <hip/hip_bf16.h>
#include <stdint.h>

// ---------------------------------------------------------------------------
// NRI-style MLP encoder. B=32, T=50, N=100, D=4, E=9900, H=256. fp32 I/O.
// R7 key insight: the "send" contributions are NODE-level GEMMs:
//   Hs = h @ W2a_send        (3200x256, once)   t2 = relu(U_i + Hs_j)  [no GEMM]
//   Vs = v2 @ W4a_send       (3200x256, once)
//   z4 = relu(C4_i + Vs_j + t2 @ (w2b@W4a_e))   [only K=256 edge GEMM]
//   out = z4 @ (w4b@wo) + (b4b@wo + bo)
// phaseA GEMM -> coalesced colsum of relu(U_i+Hs_j); phaseB K 512->256.
// Edge MFMA 215 -> 54 GFLOP; per-block L2 traffic ~640KB -> ~180KB (R6 was
// L2-traffic-bound: R4->R6 traffic ratio 1.21 matched dur ratio 1.12).
// LDS: t2 64x264 (33792B) + Vs 50x260 (26000B) = 59792 <= 64KB.
// Workspace ~11.15 MB (<= 11.2 proven). 13 dispatches.
// ---------------------------------------------------------------------------

typedef __attribute__((ext_vector_type(8))) short short8;
typedef __attribute__((ext_vector_type(4))) float float4v;
typedef __attribute__((ext_vector_type(4))) unsigned short ushort4v;

__device__ inline float bf2f(unsigned short u) {
    union { unsigned int i; float f; } v; v.i = ((unsigned int)u) << 16; return v.f;
}
__device__ inline unsigned short f2bf(float f) {
    union { float f; unsigned int i; } v; v.f = f;
    unsigned int i = v.i;
    return (unsigned short)((i + 0x7FFFu + ((i >> 16) & 1u)) >> 16);
}

// ---- all 9 weight packs in ONE launch. fp32 KxN -> bf16 Wp[kb][n][kk] ----
__global__ __launch_bounds__(256) void pack_all_kernel(
        const float* __restrict__ w1a, const float* __restrict__ w1b,
        const float* __restrict__ w2a, const float* __restrict__ w2b,
        const float* __restrict__ w3a, const float* __restrict__ w3b,
        const float* __restrict__ w4a,
        unsigned short* __restrict__ Wp1a, unsigned short* __restrict__ Wp1b,
        unsigned short* __restrict__ Wp2r, unsigned short* __restrict__ Wp2s,
        unsigned short* __restrict__ Wp2b, unsigned short* __restrict__ Wp3a,
        unsigned short* __restrict__ Wp3b, unsigned short* __restrict__ Wp4r,
        unsigned short* __restrict__ Wp4s) {
    int bx = blockIdx.x;
    const float* W; unsigned short* Wp; int Kin; int b0;
    if      (bx <  224) { W = w1a;             Wp = Wp1a; Kin = 200; b0 = 0;    }
    else if (bx <  480) { W = w1b;             Wp = Wp1b; Kin = 256; b0 = 224;  }
    else if (bx <  736) { W = w2a;             Wp = Wp2r; Kin = 256; b0 = 480;  }
    else if (bx <  992) { W = w2a + 256 * 256; Wp = Wp2s; Kin = 256; b0 = 736;  }
    else if (bx < 1248) { W = w2b;             Wp = Wp2b; Kin = 256; b0 = 992;  }
    else if (bx < 1504) { W = w3a;             Wp = Wp3a; Kin = 256; b0 = 1248; }
    else if (bx < 1760) { W = w3b;             Wp = Wp3b; Kin = 256; b0 = 1504; }
    else if (bx < 2016) { W = w4a;             Wp = Wp4r; Kin = 256; b0 = 1760; }
    else                { W = w4a + 256 * 256; Wp = Wp4s; Kin = 256; b0 = 2016; }
    int idx = (bx - b0) * 256 + threadIdx.x;
    int k = idx >> 8, n = idx & 255;
    unsigned short v = (k < Kin) ? f2bf(W[k * 256 + n]) : (unsigned short)0;
    Wp[((size_t)(k >> 5) * 256 + n) * 32 + (k & 31)] = v;
}

// ---- x (B,T,N,D) fp32 -> hin (B*N, 224) bf16, zero pad cols 200..223 ----
__global__ __launch_bounds__(256) void repack_x_kernel(
        const float* __restrict__ x, unsigned short* __restrict__ hin) {
    int idx = blockIdx.x * 256 + threadIdx.x;
    if (idx >= 3200 * 224) return;
    int row = idx / 224;
    int c = idx - row * 224;
    int b = row / 100, n = row - b * 100;
    unsigned short v = 0;
    if (c < 200) {
        int t = c >> 2, d = c & 3;
        v = f2bf(x[(((size_t)(b * 50 + t)) * 100 + n) * 4 + d]);
    }
    hin[(size_t)row * 224 + c] = v;
}

// ---- Wpz = pack(w2b @ w4a[512:768]) (256x256) ----
__global__ __launch_bounds__(256) void fuse_w2b4_kernel(
        const float* __restrict__ w2b, const float* __restrict__ w4a,
        unsigned short* __restrict__ Wpz) {
    int k = blockIdx.x, c = threadIdx.x;
    float s = 0.f;
    for (int t = 0; t < 256; ++t)
        s += w2b[k * 256 + t] * w4a[(size_t)(512 + t) * 256 + c];
    Wpz[((size_t)(k >> 5) * 256 + c) * 32 + (k & 31)] = f2bf(s);
}

// ---- block 0: Wf=w4b@wo, bfv=b4b@wo+bo ; block 1: b4a'=b4a+b2b@w4a_e, b2bs ----
__global__ __launch_bounds__(256) void fuse_misc_kernel(
        const float* __restrict__ w4b, const float* __restrict__ b4b,
        const float* __restrict__ wo, const float* __restrict__ bo,
        const float* __restrict__ b4a, const float* __restrict__ b2b,
        const float* __restrict__ w4a,
        float* __restrict__ Wf, float* __restrict__ bfv,
        float* __restrict__ b4ap, float* __restrict__ b2bs) {
    int k = threadIdx.x;
    if (blockIdx.x == 0) {
        float a[4] = {0.f, 0.f, 0.f, 0.f};
        for (int c = 0; c < 256; ++c) {
            float wv = w4b[k * 256 + c];
            #pragma unroll
            for (int o = 0; o < 4; ++o) a[o] += wv * wo[c * 4 + o];
        }
        #pragma unroll
        for (int o = 0; o < 4; ++o) Wf[k * 4 + o] = a[o];
        if (k < 4) {
            float s = bo[k];
            for (int c = 0; c < 256; ++c) s += b4b[c] * wo[c * 4 + k];
            bfv[k] = s;
        }
    } else {
        float s = b4a[k];
        for (int t = 0; t < 256; ++t)
            s += b2b[t] * w4a[(size_t)(512 + t) * 256 + k];
        b4ap[k] = s;
        b2bs[k] = 0.99f * b2b[k];
    }
}

// ---------------------------------------------------------------------------
// Node GEMM: C = act(A@Wp + bias). Grid (100,4), block 128.
// ---------------------------------------------------------------------------
template <bool RELU>
__global__ __launch_bounds__(128) void node_gemm_kernel(
        const unsigned short* __restrict__ A,
        const unsigned short* __restrict__ Bp,
        const float* __restrict__ bias,
        unsigned short* __restrict__ C, int K) {
    const int tid  = threadIdx.x;
    const int wave = tid >> 6;
    const int lane = tid & 63;
    const int l15  = lane & 15;
    const int quad = lane >> 4;
    const int m0   = blockIdx.x * 32 + wave * 16;
    const int n0   = blockIdx.y * 64;
    const int koff = quad * 8;

    float4v acc[4];
    #pragma unroll
    for (int ni = 0; ni < 4; ++ni) acc[ni] = (float4v)(0.0f);

    const int KB = K >> 5;
    for (int kb = 0; kb < KB; ++kb) {
        short8 af = *(const short8*)(A + (size_t)(m0 + l15) * K + kb * 32 + koff);
        short8 bf[4];
        #pragma unroll
        for (int ni = 0; ni < 4; ++ni)
            bf[ni] = *(const short8*)(Bp + ((size_t)kb * 256 + n0 + ni * 16 + l15) * 32 + koff);
        #pragma unroll
        for (int ni = 0; ni < 4; ++ni)
            acc[ni] = __builtin_amdgcn_mfma_f32_16x16x32_bf16(af, bf[ni], acc[ni], 0, 0, 0);
    }

    #pragma unroll
    for (int ni = 0; ni < 4; ++ni) {
        int col = n0 + ni * 16 + l15;
        float bv = bias[col];
        #pragma unroll
        for (int r = 0; r < 4; ++r) {
            float v = acc[ni][r] + bv;
            if (RELU) v = v > 0.f ? v : 0.f;
            C[(size_t)(m0 + quad * 4 + r) * 256 + col] = f2bf(v);
        }
    }
}

// ---- dual node GEMM (shared A, K=256): y<4 -> C0=A@Bp0+bias0; y>=4 -> C1=A@Bp1 ----
__global__ __launch_bounds__(128) void node_gemm_dual_kernel(
        const unsigned short* __restrict__ A,
        const unsigned short* __restrict__ Bp0, const float* __restrict__ bias0,
        unsigned short* __restrict__ C0,
        const unsigned short* __restrict__ Bp1, unsigned short* __restrict__ C1) {
    const int tid  = threadIdx.x;
    const int wave = tid >> 6;
    const int lane = tid & 63;
    const int l15  = lane & 15;
    const int quad = lane >> 4;
    const int m0   = blockIdx.x * 32 + wave * 16;
    const int sel  = blockIdx.y >> 2;
    const int n0   = (blockIdx.y & 3) * 64;
    const int koff = quad * 8;
    const unsigned short* Bp = sel ? Bp1 : Bp0;
    unsigned short* C = sel ? C1 : C0;

    float4v acc[4];
    #pragma unroll
    for (int ni = 0; ni < 4; ++ni) acc[ni] = (float4v)(0.0f);

    for (int kb = 0; kb < 8; ++kb) {
        short8 af = *(const short8*)(A + (size_t)(m0 + l15) * 256 + kb * 32 + koff);
        short8 bf[4];
        #pragma unroll
        for (int ni = 0; ni < 4; ++ni)
            bf[ni] = *(const short8*)(Bp + ((size_t)kb * 256 + n0 + ni * 16 + l15) * 32 + koff);
        #pragma unroll
        for (int ni = 0; ni < 4; ++ni)
            acc[ni] = __builtin_amdgcn_mfma_f32_16x16x32_bf16(af, bf[ni], acc[ni], 0, 0, 0);
    }

    #pragma unroll
    for (int ni = 0; ni < 4; ++ni) {
        int col = n0 + ni * 16 + l15;
        float bv = sel ? 0.f : bias0[col];
        #pragma unroll
        for (int r = 0; r < 4; ++r)
            C[(size_t)(m0 + quad * 4 + r) * 256 + col] = f2bf(acc[ni][r] + bv);
    }
}

// ---------------------------------------------------------------------------
// colsum: Ssc[g,c] = 0.01 * ( sum_{j=0..99} relu(U[g,c]+Hs[b,j,c])
//                             - relu(U[g,c]+Hs[b,i,c]) ).  Grid 3200, blk 256.
// Fully coalesced: 256 threads read one 512B Hs row per iteration.
// ---------------------------------------------------------------------------
__global__ __launch_bounds__(256) void colsum_kernel(
        const unsigned short* __restrict__ U, const unsigned short* __restrict__ Hs,
        unsigned short* __restrict__ Ssc) {
    const int g = blockIdx.x;
    const int b = g / 100, i = g - b * 100;
    const int c = threadIdx.x;
    const float u = bf2f(U[(size_t)g * 256 + c]);
    const unsigned short* base = Hs + (size_t)b * 100 * 256 + c;
    float s = 0.f;
    #pragma unroll 4
    for (int j = 0; j < 100; ++j) {
        float v = u + bf2f(base[(size_t)j * 256]);
        s += (v > 0.f ? v : 0.f);
    }
    float vi = u + bf2f(base[(size_t)i * 256]);
    s -= (vi > 0.f ? vi : 0.f);
    Ssc[(size_t)g * 256 + c] = f2bf(s * 0.01f);
}

// ---------------------------------------------------------------------------
// Phase B: grid (3200,2), block 256 (4 waves x 64 cols), M=64 (<=50 real).
// stage0: t2 tile = relu(U_i + Hs_j) -> LDS (elementwise, no GEMM);
//         Vs_j rows -> LDS.
// stage1: T2W GEMM K=256 (A=t2 LDS, B=Wpz global).
// epilogue: z4 = relu(C4_i + Vs_lds + T2W); out = z4@Wf + bfv (fused).
// LDS: t2 64x264x2=33792 + Vs 50x260x2=26000 = 59792 B.
// ---------------------------------------------------------------------------
__global__ __launch_bounds__(256, 2) void edge_phaseB_kernel(
        const unsigned short* __restrict__ Hs, const unsigned short* __restrict__ Vs,
        const unsigned short* __restrict__ U, const unsigned short* __restrict__ C4,
        const unsigned short* __restrict__ Wpz,
        const float* __restrict__ Wf, const float* __restrict__ bfv,
        float* __restrict__ out) {
    __shared__ __align__(16) unsigned short t2s[64 * 264];   // 33792 B
    __shared__ __align__(16) unsigned short vss[50 * 260];   // 26000 B
    const int g = blockIdx.x, hb = blockIdx.y;
    const int b = g / 100, nr = g - b * 100;
    const int nrows = hb ? 49 : 50;
    const int k0 = hb * 50;
    const int tid  = threadIdx.x;
    const int wave = tid >> 6;
    const int lane = tid & 63;
    const int l15  = lane & 15;
    const int quad = lane >> 4;
    const int n0   = wave * 64;
    const int koff = quad * 8;

    // ---- stage 0: build t2 + Vs tiles (elementwise, coalesced 8B/lane) ----
    {
        const int c = lane * 4;
        ushort4v uv = *(const ushort4v*)(U + (size_t)g * 256 + c);
        float u0 = bf2f(uv[0]), u1 = bf2f(uv[1]), u2 = bf2f(uv[2]), u3 = bf2f(uv[3]);
        for (int r = wave; r < nrows; r += 4) {
            int k = k0 + r;
            int j = k + (k >= nr ? 1 : 0);
            const size_t src = (size_t)(b * 100 + j) * 256 + c;
            ushort4v hv = *(const ushort4v*)(Hs + src);
            ushort4v vv = *(const ushort4v*)(Vs + src);
            ushort4v tv;
            float t0 = u0 + bf2f(hv[0]); tv[0] = f2bf(t0 > 0.f ? t0 : 0.f);
            float t1 = u1 + bf2f(hv[1]); tv[1] = f2bf(t1 > 0.f ? t1 : 0.f);
            float t2 = u2 + bf2f(hv[2]); tv[2] = f2bf(t2 > 0.f ? t2 : 0.f);
            float t3 = u3 + bf2f(hv[3]); tv[3] = f2bf(t3 > 0.f ? t3 : 0.f);
            *(ushort4v*)(&t2s[r * 264 + c]) = tv;
            *(ushort4v*)(&vss[r * 260 + c]) = vv;
        }
    }
    __syncthreads();

    // ---- stage 1: T2W GEMM, K=256, A from LDS, B from L2 ----
    float4v acc2[4][4];
    #pragma unroll
    for (int mi = 0; mi < 4; ++mi)
        #pragma unroll
        for (int ni = 0; ni < 4; ++ni) acc2[mi][ni] = (float4v)(0.0f);

    #pragma unroll
    for (int kb = 0; kb < 8; ++kb) {
        short8 af[4], bf[4];
        #pragma unroll
        for (int mi = 0; mi < 4; ++mi)
            af[mi] = *(const short8*)(&t2s[(mi * 16 + l15) * 264 + kb * 32 + koff]);
        #pragma unroll
        for (int ni = 0; ni < 4; ++ni)
            bf[ni] = *(const short8*)(Wpz + ((size_t)kb * 256 + n0 + ni * 16 + l15) * 32 + koff);
        #pragma unroll
        for (int mi = 0; mi < 4; ++mi)
            #pragma unroll
            for (int ni = 0; ni < 4; ++ni)
                acc2[mi][ni] = __builtin_amdgcn_mfma_f32_16x16x32_bf16(af[mi], bf[ni], acc2[mi][ni], 0, 0, 0);
    }
    __syncthreads();            // t2s A-reads done; safe to alias part over t2s

    float* part = (float*)t2s;  // [4 waves][64 rows][4] = 4096 B
    const unsigned short* Cp = C4 + (size_t)g * 256;
    float c4v[4], wfv[4][4];
    #pragma unroll
    for (int ni = 0; ni < 4; ++ni) {
        int col = n0 + ni * 16 + l15;
        c4v[ni] = bf2f(Cp[col]);
        #pragma unroll
        for (int o = 0; o < 4; ++o) wfv[ni][o] = Wf[col * 4 + o];
    }
    #pragma unroll
    for (int mi = 0; mi < 4; ++mi) {
        #pragma unroll
        for (int r = 0; r < 4; ++r) {
            int row = mi * 16 + quad * 4 + r;
            int vrow = row < 50 ? row : 0;   // pad rows: in-bounds garbage, discarded
            float p0 = 0.f, p1 = 0.f, p2 = 0.f, p3 = 0.f;
            #pragma unroll
            for (int ni = 0; ni < 4; ++ni) {
                int col = n0 + ni * 16 + l15;
                float zv = c4v[ni] + bf2f(vss[vrow * 260 + col]) + acc2[mi][ni][r];
                zv = zv > 0.f ? zv : 0.f;
                p0 += zv * wfv[ni][0];
                p1 += zv * wfv[ni][1];
                p2 += zv * wfv[ni][2];
                p3 += zv * wfv[ni][3];
            }
            #pragma unroll
            for (int m = 1; m <= 8; m <<= 1) {
                p0 += __shfl_xor(p0, m, 64);
                p1 += __shfl_xor(p1, m, 64);
                p2 += __shfl_xor(p2, m, 64);
                p3 += __shfl_xor(p3, m, 64);
            }
            if (l15 == 0) {
                float* pp = part + ((size_t)(wave * 64 + row)) * 4;
                pp[0] = p0; pp[1] = p1; pp[2] = p2; pp[3] = p3;
            }
        }
    }
    __syncthreads();

    {
        int row = tid >> 2, o = tid & 3;
        if (row < nrows) {
            float s = part[(size_t)(0 * 64 + row) * 4 + o] + part[(size_t)(1 * 64 + row) * 4 + o]
                    + part[(size_t)(2 * 64 + row) * 4 + o] + part[(size_t)(3 * 64 + row) * 4 + o]
                    + bfv[o];
            out[((size_t)b * 9900 + nr * 99 + k0 + row) * 4 + o] = s;
        }
    }
}

extern "C" void kernel_launch(void* const* d_in, const int* in_sizes, int n_in,
                              void* d_out, int out_size, void* d_ws, size_t ws_size,
                              hipStream_t stream) {
    const float* x   = (const float*)d_in[0];
    const float* w1a = (const float*)d_in[3];
    const float* b1a = (const float*)d_in[4];
    const float* w1b = (const float*)d_in[5];
    const float* b1b = (const float*)d_in[6];
    const float* w2a = (const float*)d_in[7];
    const float* b2a = (const float*)d_in[8];
    const float* w2b = (const float*)d_in[9];
    const float* b2b = (const float*)d_in[10];
    const float* w3a = (const float*)d_in[11];
    const float* b3a = (const float*)d_in[12];
    const float* w3b = (const float*)d_in[13];
    const float* b3b = (const float*)d_in[14];
    const float* w4a = (const float*)d_in[15];
    const float* b4a = (const float*)d_in[16];
    const float* w4b = (const float*)d_in[17];
    const float* b4b = (const float*)d_in[18];
    const float* wo  = (const float*)d_in[19];
    const float* bo  = (const float*)d_in[20];
    float* out = (float*)d_out;
    (void)in_sizes; (void)n_in; (void)out_size; (void)ws_size;

    char* ws = (char*)d_ws;
    size_t off = 0;
    auto alloc = [&](size_t bytes) {
        size_t o = off;
        off = (off + bytes + 255) & ~(size_t)255;
        return o;
    };
    const size_t SLOT_BF = (size_t)3200 * 256 * 2;   // 1.64 MB
    unsigned short* S_h  = (unsigned short*)(ws + alloc(SLOT_BF)); // h
    unsigned short* S_U  = (unsigned short*)(ws + alloc(SLOT_BF)); // U
    unsigned short* S_Hs = (unsigned short*)(ws + alloc(SLOT_BF)); // Hs
    unsigned short* S_Vs = (unsigned short*)(ws + alloc(SLOT_BF)); // Vs
    unsigned short* S_3  = (unsigned short*)(ws + alloc(SLOT_BF)); // t1 -> vin -> v2
    unsigned short* S_4  = (unsigned short*)(ws + alloc(SLOT_BF)); // hin -> Ssc -> t3 -> C4
    unsigned short* Wp1a = (unsigned short*)(ws + alloc(224 * 256 * 2));
    unsigned short* Wp1b = (unsigned short*)(ws + alloc(256 * 256 * 2));
    unsigned short* Wp2r = (unsigned short*)(ws + alloc(256 * 256 * 2));
    unsigned short* Wp2s = (unsigned short*)(ws + alloc(256 * 256 * 2));
    unsigned short* Wp2b = (unsigned short*)(ws + alloc(256 * 256 * 2));
    unsigned short* Wp3a = (unsigned short*)(ws + alloc(256 * 256 * 2));
    unsigned short* Wp3b = (unsigned short*)(ws + alloc(256 * 256 * 2));
    unsigned short* Wp4r = (unsigned short*)(ws + alloc(256 * 256 * 2));
    unsigned short* Wp4s = (unsigned short*)(ws + alloc(256 * 256 * 2));
    unsigned short* Wpz  = (unsigned short*)(ws + alloc(256 * 256 * 2));
    float*          Wf   = (float*)(ws + alloc(256 * 4 * 4));
    float*          bfv  = (float*)(ws + alloc(4 * 4));
    float*          b4ap = (float*)(ws + alloc(256 * 4));
    float*          b2bs = (float*)(ws + alloc(256 * 4));
    // total ~11.15 MB

    unsigned short* hin = S_4;   // [repack, g1]
    unsigned short* Ssc = S_4;   // [colsum, g4]
    unsigned short* t3  = S_4;   // [g5, g6]
    unsigned short* C4  = S_4;   // [g7d, phaseB]
    unsigned short* t1  = S_3;   // [g1, g2]
    unsigned short* vin = S_3;   // [g4, g5]
    unsigned short* v2  = S_3;   // [g6, g7d]

    // ---- prep (4 launches) ----
    hipLaunchKernelGGL(pack_all_kernel, dim3(2272), dim3(256), 0, stream,
                       w1a, w1b, w2a, w2b, w3a, w3b, w4a,
                       Wp1a, Wp1b, Wp2r, Wp2s, Wp2b, Wp3a, Wp3b, Wp4r, Wp4s);
    hipLaunchKernelGGL(fuse_w2b4_kernel, dim3(256), dim3(256), 0, stream, w2b, w4a, Wpz);
    hipLaunchKernelGGL(fuse_misc_kernel, dim3(2), dim3(256), 0, stream,
                       w4b, b4b, wo, bo, b4a, b2b, w4a, Wf, bfv, b4ap, b2bs);
    hipLaunchKernelGGL(repack_x_kernel, dim3(2800), dim3(256), 0, stream, x, hin);

    // ---- node MLP1, then U & Hs (dual) ----
    hipLaunchKernelGGL((node_gemm_kernel<true >), dim3(100, 4), dim3(128), 0, stream, hin, Wp1a, b1a, t1,  224); // g1
    hipLaunchKernelGGL((node_gemm_kernel<false>), dim3(100, 4), dim3(128), 0, stream, t1,  Wp1b, b1b, S_h, 256); // g2
    hipLaunchKernelGGL(node_gemm_dual_kernel, dim3(100, 8), dim3(128), 0, stream,
                       S_h, Wp2r, b2a, S_U, Wp2s, S_Hs);                                                          // g3d
    // ---- colsum (replaces edge phase A) ----
    hipLaunchKernelGGL(colsum_kernel, dim3(3200), dim3(256), 0, stream, S_U, S_Hs, Ssc);
    // ---- vin + node MLP3, then C4 & Vs (dual) ----
    hipLaunchKernelGGL((node_gemm_kernel<false>), dim3(100, 4), dim3(128), 0, stream, Ssc, Wp2b, b2bs, vin, 256); // g4
    hipLaunchKernelGGL((node_gemm_kernel<true >), dim3(100, 4), dim3(128), 0, stream, vin, Wp3a, b3a,  t3,  256); // g5
    hipLaunchKernelGGL((node_gemm_kernel<false>), dim3(100, 4), dim3(128), 0, stream, t3,  Wp3b, b3b,  v2,  256); // g6
    hipLaunchKernelGGL(node_gemm_dual_kernel, dim3(100, 8), dim3(128), 0, stream,
                       v2, Wp4r, b4ap, C4, Wp4s, S_Vs);                                                           // g7d
    // ---- phase B (elementwise t2 + K=256 GEMM + fused projection) ----
    hipLaunchKernelGGL(edge_phaseB_kernel, dim3(3200, 2), dim3(256), 0, stream,
                       S_Hs, S_Vs, S_U, C4, Wpz, Wf, bfv, out);
}